// Round 2
// 1351.355 us; speedup vs baseline: 1.3102x; 1.3102x over previous
//
#include <hip/hip_runtime.h>

// Problem constants (fixed by the reference):
//   x: [4,2048,4096] fp32 -> M=8192 tokens, K=4096
//   ternary_weight: [16384,4096] int32 in {-1,0,1} -> N=16384
//   out: [8192,16384] fp32
#define M_TOK 8192
#define N_OUT 16384
#define K_IN  4096

typedef int v4i __attribute__((ext_vector_type(4)));

// ---------------------------------------------------------------------------
// Kernel 1: weight int32 -> int8 pack. 4 elements per thread. (unchanged)
// ---------------------------------------------------------------------------
__global__ __launch_bounds__(256) void cvt_w_kernel(const int* __restrict__ w,
                                                    signed char* __restrict__ w8) {
    size_t i = (size_t)blockIdx.x * blockDim.x + threadIdx.x;  // over 16777216
    int4 v = ((const int4*)w)[i];
    char4 q;
    q.x = (signed char)v.x;
    q.y = (signed char)v.y;
    q.z = (signed char)v.z;
    q.w = (signed char)v.w;
    ((char4*)w8)[i] = q;
}

// ---------------------------------------------------------------------------
// Kernel 2: per-token dynamic int8 quantization. (unchanged, verified)
// ---------------------------------------------------------------------------
__global__ __launch_bounds__(256) void quant_kernel(const float* __restrict__ x,
                                                    signed char* __restrict__ qx,
                                                    float* __restrict__ scales) {
    int token = blockIdx.x;
    const float4* xr = (const float4*)(x + (size_t)token * K_IN);
    int t = threadIdx.x;

    float4 v[4];
    float m = 0.f;
#pragma unroll
    for (int u = 0; u < 4; ++u) {
        v[u] = xr[u * 256 + t];
        m = fmaxf(m, fmaxf(fmaxf(fabsf(v[u].x), fabsf(v[u].y)),
                           fmaxf(fabsf(v[u].z), fabsf(v[u].w))));
    }
#pragma unroll
    for (int off = 32; off > 0; off >>= 1) m = fmaxf(m, __shfl_xor(m, off));

    __shared__ float wmax[4];
    int lane = t & 63, w = t >> 6;
    if (lane == 0) wmax[w] = m;
    __syncthreads();
    float bm = fmaxf(fmaxf(wmax[0], wmax[1]), fmaxf(wmax[2], wmax[3]));
    float scale = fmaxf(bm, 1e-5f) / 127.0f;
    if (t == 0) scales[token] = scale;

    char4* qr = (char4*)(qx + (size_t)token * K_IN);
#pragma unroll
    for (int u = 0; u < 4; ++u) {
        float4 f = v[u];
        char4 q;
        q.x = (signed char)(int)fminf(fmaxf(rintf(f.x / scale), -128.f), 127.f);
        q.y = (signed char)(int)fminf(fmaxf(rintf(f.y / scale), -128.f), 127.f);
        q.z = (signed char)(int)fminf(fmaxf(rintf(f.z / scale), -128.f), 127.f);
        q.w = (signed char)(int)fminf(fmaxf(rintf(f.w / scale), -128.f), 127.f);
        qr[u * 256 + t] = q;
    }
}

// ---------------------------------------------------------------------------
// Kernel 3: int8 GEMM, 256x256 tile, BK=128, 8-phase counted-vmcnt schedule
// (port of the verified bf16 256² 8-phase template to i8; byte-identical
// geometry: 128 B per row per K-tile, 128 KiB double-buffered LDS).
//
// LDS layout per buffer: [ks:2][row:256][64B]. The 64B inner row segment is
// XOR-swizzled at 16B granularity via the GLOBAL source address (m173
// pattern): slot x at row r holds logical k-quarter x ^ ((r>>1)&3).
//  - staging: 4 consecutive lanes read one 64B line (16 lines/inst, 4x fewer
//    TA requests than a 16B-row-gather layout)
//  - ds_read_b128 fragments: 64 lanes spread exactly 8 dwords/bank (even)
//
// Point p (8 KB = 512 lanes x 16B) of a K-tile: rows (p&1)*128..+128 at
// ks=p>>1, issue order A0,B0,A1,B1,A2,B2,A3,B3 (2 per phase).
// Per-wave queue-order invariant (vmcnt counts this wave's outstanding):
//  - ph01's vmcnt(4): outstanding = 4 old (current buf ks1) + 4 new -> wait
//    completes current buf ks1, read by ph10/ph11 after the barrier.
//  - ph11's vmcnt(4): outstanding = next tile's 8 -> wait completes its ks0,
//    read by next body's ph00/ph01 after the barrier.
// Raw s_barrier (no compiler vmcnt(0) drain) keeps 4-8 loads in flight
// across barriers at all times; vmcnt never drains to 0 inside the loop.
// Epilogue drains vmcnt(0) before any wave can retire (a retired wave's
// in-flight global_load_lds would corrupt the next block's LDS).
// ---------------------------------------------------------------------------
#define BM 256
#define BN 256
#define BK 128
#define NKT (K_IN / BK)   // 32

#define ST(gp, lp) __builtin_amdgcn_global_load_lds(                         \
    (const __attribute__((address_space(1))) void*)(gp),                     \
    (__attribute__((address_space(3))) void*)(lp), 16, 0, 0)

#define MM(ii, jj, av, bv)                                                   \
    acc[ii][jj] = __builtin_amdgcn_mfma_i32_16x16x64_i8(av, bv, acc[ii][jj], 0, 0, 0)

#define PH(CUR, KS, H, SA, DA_, SB, DB_, VM)                                              \
  {                                                                                       \
    const v4i a0_ = *(const v4i*)(fA + (CUR)*32768 + (KS)*16384 + ((H)*4+0)*1024);        \
    const v4i a1_ = *(const v4i*)(fA + (CUR)*32768 + (KS)*16384 + ((H)*4+1)*1024);        \
    const v4i a2_ = *(const v4i*)(fA + (CUR)*32768 + (KS)*16384 + ((H)*4+2)*1024);        \
    const v4i a3_ = *(const v4i*)(fA + (CUR)*32768 + (KS)*16384 + ((H)*4+3)*1024);        \
    if ((H) == 0) {                                                                       \
      b0 = *(const v4i*)(fB + (CUR)*32768 + (KS)*16384 + 0*1024);                         \
      b1 = *(const v4i*)(fB + (CUR)*32768 + (KS)*16384 + 1*1024);                         \
      b2 = *(const v4i*)(fB + (CUR)*32768 + (KS)*16384 + 2*1024);                         \
      b3 = *(const v4i*)(fB + (CUR)*32768 + (KS)*16384 + 3*1024);                         \
    }                                                                                     \
    ST(SA, DA_);                                                                          \
    ST(SB, DB_);                                                                          \
    __builtin_amdgcn_s_barrier();                                                         \
    asm volatile("s_waitcnt lgkmcnt(0)" ::: "memory");                                    \
    __builtin_amdgcn_sched_barrier(0); /* rule #18: keep MFMA below the wait */           \
    __builtin_amdgcn_s_setprio(1);                                                        \
    MM((H)*4+0, 0, a0_, b0); MM((H)*4+0, 1, a0_, b1);                                     \
    MM((H)*4+0, 2, a0_, b2); MM((H)*4+0, 3, a0_, b3);                                     \
    MM((H)*4+1, 0, a1_, b0); MM((H)*4+1, 1, a1_, b1);                                     \
    MM((H)*4+1, 2, a1_, b2); MM((H)*4+1, 3, a1_, b3);                                     \
    MM((H)*4+2, 0, a2_, b0); MM((H)*4+2, 1, a2_, b1);                                     \
    MM((H)*4+2, 2, a2_, b2); MM((H)*4+2, 3, a2_, b3);                                     \
    MM((H)*4+3, 0, a3_, b0); MM((H)*4+3, 1, a3_, b1);                                     \
    MM((H)*4+3, 2, a3_, b2); MM((H)*4+3, 3, a3_, b3);                                     \
    __builtin_amdgcn_s_setprio(0);                                                        \
    if (VM) asm volatile("s_waitcnt vmcnt(4)" ::: "memory");                              \
    __builtin_amdgcn_s_barrier();                                                         \
  }

#define TILEBODY(CUR, KTN)                                                  \
  {                                                                         \
    const signed char* pa0 = gA0 + (KTN) * 128;                             \
    const signed char* pa1 = gA1 + (KTN) * 128;                             \
    const signed char* pb0 = gB0 + (KTN) * 128;                             \
    const signed char* pb1 = gB1 + (KTN) * 128;                             \
    signed char* dA = ldsA + ((CUR) ^ 1) * 32768 + wb;                      \
    signed char* dB = ldsB + ((CUR) ^ 1) * 32768 + wb;                      \
    v4i b0, b1, b2, b3;                                                     \
    PH(CUR, 0, 0, pa0,      dA,         pb0,      dB,         0)            \
    PH(CUR, 0, 1, pa1,      dA +  8192, pb1,      dB +  8192, 1)            \
    PH(CUR, 1, 0, pa0 + 64, dA + 16384, pb0 + 64, dB + 16384, 0)            \
    PH(CUR, 1, 1, pa1 + 64, dA + 24576, pb1 + 64, dB + 24576, 1)            \
  }

__global__ __launch_bounds__(512, 2) void gemm_kernel(
    const signed char* __restrict__ A,   // [M_TOK][K_IN] qx
    const signed char* __restrict__ B,   // [N_OUT][K_IN] w8
    const float* __restrict__ scales,    // [M_TOK]
    const float* __restrict__ wscale,    // [1]
    const float* __restrict__ bias,      // [N_OUT]
    float* __restrict__ out)             // [M_TOK][N_OUT]
{
    __shared__ __align__(16) signed char smA[2][2][256][64];  // 64 KB
    __shared__ __align__(16) signed char smB[2][2][256][64];  // 64 KB

    const int t = threadIdx.x;
    const int lane = t & 63;
    const int w = t >> 6;          // 0..7
    const int wm = w >> 2;         // 0..1  (M-half of the wave grid)
    const int wn = w & 3;          // 0..3  (N-quarter)

    // XCD-aware bijective swizzle: 2048 blocks = 8 XCD x 256; per-XCD chunk
    // walks 4x4 supertiles so concurrent blocks share A/B panels in L2.
    const int bid = blockIdx.x;
    const int xcd = bid & 7;
    const int c   = bid >> 3;                     // 0..255
    const int mt  = xcd * 4 + ((c & 15) >> 2);    // 0..31
    const int nt  = (c >> 4) * 4 + (c & 3);       // 0..63
    const int m0 = mt * BM;
    const int n0 = nt * BN;

    // staging lane geometry: chunk = (row within half, 16B slot); the global
    // slot is XOR-pre-swizzled so LDS slot x at row r holds k-quarter
    // x ^ ((r>>1)&3). (row>>1)&3 == (srow>>1)&3 for both 128-row halves.
    const int srow = t >> 2;                 // 0..127
    const int sx   = t & 3;
    const int kq   = sx ^ ((srow >> 1) & 3);
    const signed char* gA0 = A + (size_t)(m0 + srow) * K_IN + kq * 16;  // rows 0-127
    const signed char* gA1 = gA0 + (size_t)128 * K_IN;                  // rows 128-255
    const signed char* gB0 = B + (size_t)(n0 + srow) * K_IN + kq * 16;
    const signed char* gB1 = gB0 + (size_t)128 * K_IN;

    signed char* ldsA = &smA[0][0][0][0];
    signed char* ldsB = &smB[0][0][0][0];
    const int wb = w * 1024;   // wave-uniform stage base (HW adds lane*16)

    // fragment read bases: logical k-quarter g of row R0+r lives at swizzled
    // slot g ^ ((r>>1)&3)  (R0 multiple of 16 -> swizzle depends on r only)
    const int r = lane & 15, g = lane >> 4;
    const int fsl = (g ^ ((r >> 1) & 3)) * 16;
    const signed char* fA = ldsA + (wm * 128 + r) * 64 + fsl;
    const signed char* fB = ldsB + (wn * 64 + r) * 64 + fsl;

    v4i acc[8][4] = {};

    // Prologue: tile 0 -> buf 0, issue order A0,B0,A1,B1,A2,B2,A3,B3.
    // vmcnt(4): oldest 4 (= ks0 points A0,B0,A1,B1) resident before ph0.
    ST(gA0,      ldsA + 0 * 8192 + wb);
    ST(gB0,      ldsB + 0 * 8192 + wb);
    ST(gA1,      ldsA + 1 * 8192 + wb);
    ST(gB1,      ldsB + 1 * 8192 + wb);
    ST(gA0 + 64, ldsA + 2 * 8192 + wb);
    ST(gB0 + 64, ldsB + 2 * 8192 + wb);
    ST(gA1 + 64, ldsA + 3 * 8192 + wb);
    ST(gB1 + 64, ldsB + 3 * 8192 + wb);
    asm volatile("s_waitcnt vmcnt(4)" ::: "memory");
    __builtin_amdgcn_s_barrier();

    // Main loop: 2 K-tiles per iteration (compile-time buffer parity).
    // Last iteration's prefetch wraps to tile 0 (64 KB of L2-warm waste).
    for (int kt = 0; kt < NKT; kt += 2) {
        TILEBODY(0, kt + 1)
        TILEBODY(1, (kt + 2) & (NKT - 1))
    }

    // Drain ALL outstanding global_load_lds before any wave can retire:
    // a late-landing LDS write after workgroup dealloc would corrupt the
    // next block's LDS on this CU ("epilogue drains ...->0", m194 template).
    asm volatile("s_waitcnt vmcnt(0)" ::: "memory");

    // Epilogue: out = acc * scales[m]*wsc + bias[n]
    // C/D map (verified): col = lane&15, row = (lane>>4)*4 + reg
    const float wsc = wscale[0];
    const int col0 = n0 + wn * 64 + r;
    const int rbase = g * 4;
    float bj[4];
#pragma unroll
    for (int j = 0; j < 4; ++j) bj[j] = bias[col0 + j * 16];
#pragma unroll
    for (int i = 0; i < 8; ++i) {
        const int rowA = m0 + wm * 128 + i * 16 + rbase;
#pragma unroll
        for (int rr = 0; rr < 4; ++rr) {
            const float as_ = scales[rowA + rr] * wsc;
            float* orow = out + (size_t)(rowA + rr) * N_OUT;
#pragma unroll
            for (int j = 0; j < 4; ++j) {
                orow[col0 + j * 16] = (float)acc[i][j][rr] * as_ + bj[j];
            }
        }
    }
}

// ---------------------------------------------------------------------------
extern "C" void kernel_launch(void* const* d_in, const int* in_sizes, int n_in,
                              void* d_out, int out_size, void* d_ws, size_t ws_size,
                              hipStream_t stream) {
    const float* x      = (const float*)d_in[0];   // [8192*4096] fp32
    const int*   tw     = (const int*)d_in[1];     // [16384*4096] int32
    const float* wscale = (const float*)d_in[2];   // [1]
    const float* bias   = (const float*)d_in[3];   // [16384]
    float* out = (float*)d_out;                    // [8192*16384] fp32

    // workspace layout: qx (32MB) | w8 (64MB) | scales (32KB)
    signed char* qx = (signed char*)d_ws;
    signed char* w8 = qx + (size_t)M_TOK * K_IN;
    float* scales = (float*)(w8 + (size_t)N_OUT * K_IN);

    cvt_w_kernel<<<65536, 256, 0, stream>>>(tw, w8);
    quant_kernel<<<M_TOK, 256, 0, stream>>>(x, qx, scales);
    // 8 XCD x 256 = 2048 blocks of 512 threads (one 256x256 tile each)
    gemm_kernel<<<2048, 512, 0, stream>>>(qx, w8, scales, wscale, bias, out);
}

// Round 4
// 1257.771 us; speedup vs baseline: 1.4077x; 1.0744x over previous
//
#include <hip/hip_runtime.h>

// Problem constants (fixed by the reference):
//   x: [4,2048,4096] fp32 -> M=8192 tokens, K=4096
//   ternary_weight: [16384,4096] int32 in {-1,0,1} -> N=16384
//   out: [8192,16384] fp32
#define M_TOK 8192
#define N_OUT 16384
#define K_IN  4096

typedef int   v4i  __attribute__((ext_vector_type(4)));
typedef int   v16i __attribute__((ext_vector_type(16)));
typedef float v4f  __attribute__((ext_vector_type(4)));
typedef signed char v4c __attribute__((ext_vector_type(4)));

// ---------------------------------------------------------------------------
// Kernel 1: fused prep = per-token int8 quant (blocks 0..8191) +
//           weight int32->int8 pack (blocks 8192..73727).
// One launch so the two memory-bound passes overlap on the device.
// Single-use inputs (x, ternary_weight int32) are read non-temporally so
// they don't evict qx/w8 (which the GEMM is about to re-read) from L2/L3.
// Branch is wave-uniform (on blockIdx); the weight branch has no barrier.
// ---------------------------------------------------------------------------
__global__ __launch_bounds__(256) void prep_kernel(const int* __restrict__ w,
                                                   signed char* __restrict__ w8,
                                                   const float* __restrict__ x,
                                                   signed char* __restrict__ qx,
                                                   float* __restrict__ scales) {
    const int b = blockIdx.x;
    const int t = threadIdx.x;

    if (b >= 8192) {
        // ---- weight pack: 16384*4096/4 = 16777216 v4i chunks ----
        size_t i = (size_t)(b - 8192) * 256 + t;
        v4i v = __builtin_nontemporal_load(&((const v4i*)w)[i]);
        v4c q;
        q[0] = (signed char)v[0];
        q[1] = (signed char)v[1];
        q[2] = (signed char)v[2];
        q[3] = (signed char)v[3];
        ((v4c*)w8)[i] = q;   // cached: GEMM reads this next
        return;
    }

    // ---- per-token dynamic int8 quantization (token = b) ----
    const int token = b;
    const v4f* xr = (const v4f*)(x + (size_t)token * K_IN);

    v4f v[4];
    float m = 0.f;
#pragma unroll
    for (int u = 0; u < 4; ++u) {
        v[u] = __builtin_nontemporal_load(&xr[u * 256 + t]);
        m = fmaxf(m, fmaxf(fmaxf(fabsf(v[u][0]), fabsf(v[u][1])),
                           fmaxf(fabsf(v[u][2]), fabsf(v[u][3]))));
    }
#pragma unroll
    for (int off = 32; off > 0; off >>= 1) m = fmaxf(m, __shfl_xor(m, off));

    __shared__ float wmax[4];
    int lane = t & 63, wv = t >> 6;
    if (lane == 0) wmax[wv] = m;
    __syncthreads();
    float bm = fmaxf(fmaxf(wmax[0], wmax[1]), fmaxf(wmax[2], wmax[3]));
    float scale = fmaxf(bm, 1e-5f) / 127.0f;
    if (t == 0) scales[token] = scale;

    v4c* qr = (v4c*)(qx + (size_t)token * K_IN);
#pragma unroll
    for (int u = 0; u < 4; ++u) {
        v4c q;
        q[0] = (signed char)(int)fminf(fmaxf(rintf(v[u][0] / scale), -128.f), 127.f);
        q[1] = (signed char)(int)fminf(fmaxf(rintf(v[u][1] / scale), -128.f), 127.f);
        q[2] = (signed char)(int)fminf(fmaxf(rintf(v[u][2] / scale), -128.f), 127.f);
        q[3] = (signed char)(int)fminf(fmaxf(rintf(v[u][3] / scale), -128.f), 127.f);
        qr[u * 256 + t] = q;   // cached: GEMM reads this next
    }
}

// ---------------------------------------------------------------------------
// Kernel 2: int8 GEMM, 256x256 tile, BK=128, 8-phase counted-vmcnt schedule.
// Round-2 VERIFIED schedule kept exactly (barriers, vmcnt(4) trace, staging
// layout, XOR swizzle, epilogue vmcnt(0) drain). Round-3 changes:
//   * mfma_i32_32x32x32_i8 (8 big MFMAs/phase instead of 16 small; 4404 vs
//     3944 TOPS ubench, half the issue slots in the setprio window)
//   * non-temporal epilogue stores (output never re-read; stop thrashing
//     L2/L3 so the 96 MB A/B input set stays resident for staging)
//
// LDS layout per buffer: [ks:2][row:256][64B]; 64B row = K=64 section in 4
// XOR-swizzled 16B quarters: quarter q of row r lives at slot q ^ ((r>>1)&3).
// 32x32x32 A/B fragment (canonical 2-group ext. of the verified 16x16x64
// map): lane reads row r32=lane&31, 16 k-bytes at k-quarter (2h + (lane>>5))
// -> LDS slot ((2h+g2) ^ xr), xr=(r32>>1)&3 (tile row base mult. of 32).
// Bank check: 8-row groups start banks {0,16,0,16,8,24,8,24}, 8 dwords each
// -> exactly 8 dwords/bank across the wave: even, conflict-free.
//
// Per-wave vmcnt trace (steady state, 2 loads/phase, 8 points/K-tile):
//   entry: 4 outstanding (current ks1)
//   ph(0,0): read ks0; issue A0,B0            -> 6
//   ph(0,1): read ks0; issue A1,B1 -> 8; vmcnt(4) completes current ks1
//   ph(1,0): read ks1; issue A0',B0'          -> 6
//   ph(1,1): read ks1; issue A1',B1' -> 8; vmcnt(4) completes next ks0
//   exit: 4 outstanding. Epilogue drains vmcnt(0) before any wave retires.
// ---------------------------------------------------------------------------
#define BM 256
#define BN 256
#define BK 128
#define NKT (K_IN / BK)   // 32

#define ST(gp, lp) __builtin_amdgcn_global_load_lds(                         \
    (const __attribute__((address_space(1))) void*)(gp),                     \
    (__attribute__((address_space(3))) void*)(lp), 16, 0, 0)

#define MM(ii, jj, av, bv)                                                   \
    acc[ii][jj] = __builtin_amdgcn_mfma_i32_32x32x32_i8(av, bv, acc[ii][jj], 0, 0, 0)

#define PH(CUR, KS, H, SA, DA_, SB, DB_, VM)                                              \
  {                                                                                       \
    const signed char* fa_ = ((H) ? fA1 : fA0) + (CUR)*32768 + (KS)*16384;                \
    const signed char* fb_ = ((H) ? fB1 : fB0) + (CUR)*32768 + (KS)*16384;                \
    const v4i a0_ = *(const v4i*)(fa_ + 0*2048);                                          \
    const v4i a1_ = *(const v4i*)(fa_ + 1*2048);                                          \
    const v4i a2_ = *(const v4i*)(fa_ + 2*2048);                                          \
    const v4i a3_ = *(const v4i*)(fa_ + 3*2048);                                          \
    const v4i b0_ = *(const v4i*)(fb_ + 0*2048);                                          \
    const v4i b1_ = *(const v4i*)(fb_ + 1*2048);                                          \
    ST(SA, DA_);                                                                          \
    ST(SB, DB_);                                                                          \
    __builtin_amdgcn_s_barrier();                                                         \
    asm volatile("s_waitcnt lgkmcnt(0)" ::: "memory");                                    \
    __builtin_amdgcn_sched_barrier(0); /* rule #18: keep MFMA below the wait */           \
    __builtin_amdgcn_s_setprio(1);                                                        \
    MM(0, 0, a0_, b0_); MM(0, 1, a0_, b1_);                                               \
    MM(1, 0, a1_, b0_); MM(1, 1, a1_, b1_);                                               \
    MM(2, 0, a2_, b0_); MM(2, 1, a2_, b1_);                                               \
    MM(3, 0, a3_, b0_); MM(3, 1, a3_, b1_);                                               \
    __builtin_amdgcn_s_setprio(0);                                                        \
    if (VM) asm volatile("s_waitcnt vmcnt(4)" ::: "memory");                              \
    __builtin_amdgcn_s_barrier();                                                         \
  }

#define TILEBODY(CUR, KTN)                                                  \
  {                                                                         \
    const signed char* pa0 = gA0 + (KTN) * 128;                             \
    const signed char* pa1 = gA1 + (KTN) * 128;                             \
    const signed char* pb0 = gB0 + (KTN) * 128;                             \
    const signed char* pb1 = gB1 + (KTN) * 128;                             \
    signed char* dA = ldsA + ((CUR) ^ 1) * 32768 + wb;                      \
    signed char* dB = ldsB + ((CUR) ^ 1) * 32768 + wb;                      \
    PH(CUR, 0, 0, pa0,      dA,         pb0,      dB,         0)            \
    PH(CUR, 0, 1, pa1,      dA +  8192, pb1,      dB +  8192, 1)            \
    PH(CUR, 1, 0, pa0 + 64, dA + 16384, pb0 + 64, dB + 16384, 0)            \
    PH(CUR, 1, 1, pa1 + 64, dA + 24576, pb1 + 64, dB + 24576, 1)            \
  }

__global__ __launch_bounds__(512, 2) void gemm_kernel(
    const signed char* __restrict__ A,   // [M_TOK][K_IN] qx
    const signed char* __restrict__ B,   // [N_OUT][K_IN] w8
    const float* __restrict__ scales,    // [M_TOK]
    const float* __restrict__ wscale,    // [1]
    const float* __restrict__ bias,      // [N_OUT]
    float* __restrict__ out)             // [M_TOK][N_OUT]
{
    __shared__ __align__(16) signed char smA[2][2][256][64];  // 64 KB
    __shared__ __align__(16) signed char smB[2][2][256][64];  // 64 KB

    const int t = threadIdx.x;
    const int lane = t & 63;
    const int w = t >> 6;          // 0..7
    const int wm = w >> 2;         // 0..1  (M-half of the wave grid)
    const int wn = w & 3;          // 0..3  (N-quarter)

    // XCD-aware bijective swizzle: 2048 blocks = 8 XCD x 256; per-XCD chunk
    // walks 4x4 supertiles so concurrent blocks share A/B panels in L2.
    const int bid = blockIdx.x;
    const int xcd = bid & 7;
    const int c   = bid >> 3;                     // 0..255
    const int mt  = xcd * 4 + ((c & 15) >> 2);    // 0..31
    const int nt  = (c >> 4) * 4 + (c & 3);       // 0..63
    const int m0 = mt * BM;
    const int n0 = nt * BN;

    // staging lane geometry: the global slot is XOR-pre-swizzled so LDS slot
    // x at row r holds k-quarter x ^ ((r>>1)&3) (both 128-row halves).
    const int srow = t >> 2;                 // 0..127
    const int sx   = t & 3;
    const int kq   = sx ^ ((srow >> 1) & 3);
    const signed char* gA0 = A + (size_t)(m0 + srow) * K_IN + kq * 16;  // rows 0-127
    const signed char* gA1 = gA0 + (size_t)128 * K_IN;                  // rows 128-255
    const signed char* gB0 = B + (size_t)(n0 + srow) * K_IN + kq * 16;
    const signed char* gB1 = gB0 + (size_t)128 * K_IN;

    signed char* ldsA = &smA[0][0][0][0];
    signed char* ldsB = &smB[0][0][0][0];
    const int wb = w * 1024;   // wave-uniform stage base (HW adds lane*16)

    // 32x32 fragment read bases: row r32 = lane&31, group g2 = lane>>5.
    // Logical quarter (2h+g2) of row R0+r32 lives at slot (2h+g2)^xr,
    // xr = (r32>>1)&3  (R0 is a multiple of 32 -> xr lane-only).
    // h=1 slot = h=0 slot XOR 2 -> byte offset XOR 32: two precomputed bases.
    const int r32 = lane & 31;
    const int g2  = lane >> 5;
    const int xr  = (r32 >> 1) & 3;
    const int sl0 = (g2 ^ xr) * 16;
    const int sl1 = ((g2 ^ xr) ^ 2) * 16;
    const signed char* fA0 = ldsA + wm * 8192 + r32 * 64 + sl0;
    const signed char* fA1 = ldsA + wm * 8192 + r32 * 64 + sl1;
    const signed char* fB0 = ldsB + wn * 4096 + r32 * 64 + sl0;
    const signed char* fB1 = ldsB + wn * 4096 + r32 * 64 + sl1;

    v16i acc[4][2] = {};   // 4 M-tiles x 2 N-tiles of 32x32

    // Prologue: tile 0 -> buf 0, issue order A0,B0,A1,B1,A2,B2,A3,B3.
    // vmcnt(4): oldest 4 (= ks0 points) resident before phase (0,0).
    ST(gA0,      ldsA + 0 * 8192 + wb);
    ST(gB0,      ldsB + 0 * 8192 + wb);
    ST(gA1,      ldsA + 1 * 8192 + wb);
    ST(gB1,      ldsB + 1 * 8192 + wb);
    ST(gA0 + 64, ldsA + 2 * 8192 + wb);
    ST(gB0 + 64, ldsB + 2 * 8192 + wb);
    ST(gA1 + 64, ldsA + 3 * 8192 + wb);
    ST(gB1 + 64, ldsB + 3 * 8192 + wb);
    asm volatile("s_waitcnt vmcnt(4)" ::: "memory");
    __builtin_amdgcn_s_barrier();

    // Main loop: 2 K-tiles per iteration (compile-time buffer parity).
    // Last iteration's prefetch wraps to tile 0 (64 KB of L2-warm waste).
    for (int kt = 0; kt < NKT; kt += 2) {
        TILEBODY(0, kt + 1)
        TILEBODY(1, (kt + 2) & (NKT - 1))
    }

    // Drain ALL outstanding global_load_lds before any wave can retire
    // (late-landing LDS write would corrupt the next block on this CU).
    asm volatile("s_waitcnt vmcnt(0)" ::: "memory");

    // Epilogue: out = acc * scales[m]*wsc + bias[n]
    // 32x32 C/D map (m74/m101, dtype-independent): col = lane&31,
    // row = (reg&3) + 8*(reg>>2) + 4*(lane>>5).
    // Non-temporal: output is never re-read; keep inputs resident in L2/L3.
    const float wsc = wscale[0];
    const int col0 = n0 + wn * 64 + r32;
    const float bj0 = bias[col0];
    const float bj1 = bias[col0 + 32];
#pragma unroll
    for (int i = 0; i < 4; ++i) {
#pragma unroll
        for (int reg = 0; reg < 16; ++reg) {
            const int row = m0 + wm * 128 + i * 32 + 4 * g2 + (reg & 3) + 8 * (reg >> 2);
            const float as_ = scales[row] * wsc;
            float* orow = out + (size_t)row * N_OUT;
            __builtin_nontemporal_store((float)acc[i][0][reg] * as_ + bj0, &orow[col0]);
            __builtin_nontemporal_store((float)acc[i][1][reg] * as_ + bj1, &orow[col0 + 32]);
        }
    }
}

// ---------------------------------------------------------------------------
extern "C" void kernel_launch(void* const* d_in, const int* in_sizes, int n_in,
                              void* d_out, int out_size, void* d_ws, size_t ws_size,
                              hipStream_t stream) {
    const float* x      = (const float*)d_in[0];   // [8192*4096] fp32
    const int*   tw     = (const int*)d_in[1];     // [16384*4096] int32
    const float* wscale = (const float*)d_in[2];   // [1]
    const float* bias   = (const float*)d_in[3];   // [16384]
    float* out = (float*)d_out;                    // [8192*16384] fp32

    // workspace layout: qx (32MB) | w8 (64MB) | scales (32KB)
    signed char* qx = (signed char*)d_ws;
    signed char* w8 = qx + (size_t)M_TOK * K_IN;
    float* scales = (float*)(w8 + (size_t)N_OUT * K_IN);

    // fused prep: blocks 0..8191 quant, 8192..73727 weight pack
    prep_kernel<<<73728, 256, 0, stream>>>(tw, w8, x, qx, scales);
    // 8 XCD x 256 = 2048 blocks of 512 threads (one 256x256 tile each)
    gemm_kernel<<<2048, 512, 0, stream>>>(qx, w8, scales, wscale, bias, out);
}